// Round 8
// baseline (59.835 us; speedup 1.0000x reference)
//
#include <hip/hip_runtime.h>
#include <stdint.h>

// Problem constants
#define M_ROWS   16000        // B*T
#define N_RT_PAD 1008         // 126 row-blocks x 8 tiles
#define D_IN     320
#define E_DIM    16
#define K_CB     8192
#define NCHUNK   32           // k-chunks (16 k-tiles each)
#define KT_PER_CHUNK 16
#define NRB      126          // row-blocks (8 rt each; 2 rt per wave)

typedef __attribute__((ext_vector_type(8))) short bf16x8;
typedef __attribute__((ext_vector_type(4))) float f32x4;

// Workspace layout (bytes)
#define XA_OFF   0u                       // [1008 tiles][64 lanes][8 bf16]  (h|m)
#define XB_OFF   1032192u                 // same shape                       (l|h)
#define CBA_OFF  2064384u                 // [512 ktiles][64 lanes][8 bf16]  (h'|m')
#define CBC_OFF  2588672u                 // same                             (h'|l')
#define PART_OFF 3112960u                 // [16000 rows][32 kc] u64 partials

#define AS1 __attribute__((address_space(1)))
#define AS3 __attribute__((address_space(3)))

__device__ __forceinline__ unsigned short f2bf(float x) {
    union { float f; unsigned u; } v; v.f = x;
    unsigned r = v.u + 0x7FFFu + ((v.u >> 16) & 1u);   // round-to-nearest-even
    return (unsigned short)(r >> 16);
}
__device__ __forceinline__ float bf2f(unsigned short b) {
    union { unsigned u; float f; } v; v.u = ((unsigned)b) << 16; return v.f;
}

// ---------- Fused prep: projection-split-pack (blocks 0..249) + codebook
// split-pack (blocks 250..377). Math identical to rounds 2-7. ----------
__global__ __launch_bounds__(256) void prep_kernel(const float* __restrict__ hs,
                                                   const float* __restrict__ P,
                                                   const float* __restrict__ CB,
                                                   unsigned short* __restrict__ Xa,
                                                   unsigned short* __restrict__ Xb,
                                                   unsigned short* __restrict__ CBa,
                                                   unsigned short* __restrict__ CBc) {
    int bid = blockIdx.x;
    int t   = threadIdx.x;
    if (bid < 250) {
        int row = bid * 64 + (t >> 2);
        int eq  = t & 3;
        if (row >= M_ROWS) return;
        const float* hrow = hs + (size_t)row * D_IN;
        float ax = 0.f, ay = 0.f, az = 0.f, aw = 0.f;
        #pragma unroll 4
        for (int d = 0; d < D_IN; d += 4) {
            float4 h4 = *reinterpret_cast<const float4*>(hrow + d);
            float4 p0 = *reinterpret_cast<const float4*>(P + (size_t)(d + 0) * E_DIM + eq * 4);
            float4 p1 = *reinterpret_cast<const float4*>(P + (size_t)(d + 1) * E_DIM + eq * 4);
            float4 p2 = *reinterpret_cast<const float4*>(P + (size_t)(d + 2) * E_DIM + eq * 4);
            float4 p3 = *reinterpret_cast<const float4*>(P + (size_t)(d + 3) * E_DIM + eq * 4);
            ax += h4.x * p0.x + h4.y * p1.x + h4.z * p2.x + h4.w * p3.x;
            ay += h4.x * p0.y + h4.y * p1.y + h4.z * p2.y + h4.w * p3.y;
            az += h4.x * p0.z + h4.y * p1.z + h4.z * p2.z + h4.w * p3.z;
            aw += h4.x * p0.w + h4.y * p1.w + h4.z * p2.w + h4.w * p3.w;
        }
        float v[4] = {ax, ay, az, aw};
        ushort4 h, m, l;
        unsigned short* hp = (unsigned short*)&h;
        unsigned short* mp = (unsigned short*)&m;
        unsigned short* lp = (unsigned short*)&l;
        #pragma unroll
        for (int i = 0; i < 4; ++i) {
            unsigned short hb = f2bf(v[i]);      float r1 = v[i] - bf2f(hb);
            unsigned short mb = f2bf(r1);        float r2 = r1 - bf2f(mb);
            unsigned short lb = f2bf(r2);        // exact: v = h + m + l
            hp[i] = hb; mp[i] = mb; lp[i] = lb;
        }
        int rt = row >> 4, rl = row & 15;
        int g  = eq >> 1;
        int j0 = (eq & 1) * 4;
        size_t base = (size_t)rt * 512;
        *reinterpret_cast<ushort4*>(Xa + base + ((g    ) * 16 + rl) * 8 + j0) = h;
        *reinterpret_cast<ushort4*>(Xa + base + ((2 + g) * 16 + rl) * 8 + j0) = m;
        *reinterpret_cast<ushort4*>(Xb + base + ((g    ) * 16 + rl) * 8 + j0) = l;
        *reinterpret_cast<ushort4*>(Xb + base + ((2 + g) * 16 + rl) * 8 + j0) = h;
    } else {
        int bid2 = bid - 250;                     // 0..127
        int c  = bid2 * 64 + (t >> 2);
        int eq = t & 3;
        float4 v4 = *reinterpret_cast<const float4*>(CB + (size_t)c * E_DIM + eq * 4);
        float v[4] = {v4.x, v4.y, v4.z, v4.w};
        ushort4 h, m, l;
        unsigned short* hp = (unsigned short*)&h;
        unsigned short* mp = (unsigned short*)&m;
        unsigned short* lp = (unsigned short*)&l;
        #pragma unroll
        for (int i = 0; i < 4; ++i) {
            unsigned short hb = f2bf(v[i]);      float r1 = v[i] - bf2f(hb);
            unsigned short mb = f2bf(r1);        float r2 = r1 - bf2f(mb);
            unsigned short lb = f2bf(r2);
            hp[i] = hb; mp[i] = mb; lp[i] = lb;
        }
        int kt = c >> 4, cl = c & 15;
        int g  = eq >> 1;
        int j0 = (eq & 1) * 4;
        size_t base = (size_t)kt * 512;
        *reinterpret_cast<ushort4*>(CBa + base + ((g    ) * 16 + cl) * 8 + j0) = h;
        *reinterpret_cast<ushort4*>(CBa + base + ((2 + g) * 16 + cl) * 8 + j0) = m;
        *reinterpret_cast<ushort4*>(CBc + base + ((g    ) * 16 + cl) * 8 + j0) = h;
        *reinterpret_cast<ushort4*>(CBc + base + ((2 + g) * 16 + cl) * 8 + j0) = l;
    }
}

// ---------- MFMA score + fused argmax; whole-chunk LDS staging ----------
// 4032 blocks x 256 threads (4 waves). Block stages its k-chunk's full B
// fragments (16 kt x 2 streams = 32 KB) via global_load_lds (0 VGPR cost),
// ONE __syncthreads (compiler emits the vmcnt drain), then a barrier-free
// loop: ds_read_b128 + 3 chained MFMAs (exact fp32-split scores) + strict-gt
// argmax. Wave owns 2 row-tiles. u64-key shfl reduce; plain store to
// part[row][kc]; decode kernel reduces the 32 partials per row.
__global__ __launch_bounds__(256, 4) void score_kernel(const unsigned short* __restrict__ Xa,
                                                       const unsigned short* __restrict__ Xb,
                                                       const unsigned short* __restrict__ CBa,
                                                       const unsigned short* __restrict__ CBc,
                                                       unsigned long long* __restrict__ part) {
    __shared__ unsigned short sA[KT_PER_CHUNK * 512];   // 16 KB  (h'|m')
    __shared__ unsigned short sC[KT_PER_CHUNK * 512];   // 16 KB  (h'|l')

    int t    = threadIdx.x;
    int lane = t & 63;
    int w    = t >> 6;                // 0..3
    int flat = blockIdx.x;            // 0..4031
    int xcd  = flat & 7;
    int idx  = flat >> 3;             // 0..503
    int kc   = xcd * 4 + idx / NRB;   // 0..31, clustered per XCD
    int rb   = idx % NRB;             // 0..125
    int rt0  = rb * 8 + w * 2;

    // Issue A-fragment loads early (results needed after the barrier).
    bf16x8 a_hm[2], a_lh[2];
    #pragma unroll
    for (int r = 0; r < 2; ++r) {
        a_hm[r] = *reinterpret_cast<const bf16x8*>(Xa + ((size_t)(rt0 + r) * 64 + lane) * 8);
        a_lh[r] = *reinterpret_cast<const bf16x8*>(Xb + ((size_t)(rt0 + r) * 64 + lane) * 8);
    }

    // Stage both B streams for the whole k-chunk: 4 glds rounds each,
    // dst = wave-uniform base + lane*16 (HW scatter), src per-lane.
    {
        const unsigned char* ga = (const unsigned char*)(CBa + (size_t)kc * KT_PER_CHUNK * 512);
        const unsigned char* gc = (const unsigned char*)(CBc + (size_t)kc * KT_PER_CHUNK * 512);
        unsigned char* la = (unsigned char*)sA;
        unsigned char* lc = (unsigned char*)sC;
        int wo = w * 1024 + lane * 16;
        #pragma unroll
        for (int q = 0; q < 4; ++q)
            __builtin_amdgcn_global_load_lds((const AS1 void*)(ga + q * 4096 + wo),
                                             (AS3 void*)(la + q * 4096 + w * 1024), 16, 0, 0);
        #pragma unroll
        for (int q = 0; q < 4; ++q)
            __builtin_amdgcn_global_load_lds((const AS1 void*)(gc + q * 4096 + wo),
                                             (AS3 void*)(lc + q * 4096 + w * 1024), 16, 0, 0);
    }

    float best[2][4];
    int   bidx[2][4];
    #pragma unroll
    for (int r = 0; r < 2; ++r)
        #pragma unroll
        for (int i = 0; i < 4; ++i) { best[r][i] = -3.0e38f; bidx[r][i] = 0; }

    __syncthreads();   // compiler emits vmcnt(0) drain: staging + A-loads done

    const bf16x8* sA8 = reinterpret_cast<const bf16x8*>(sA);
    const bf16x8* sC8 = reinterpret_cast<const bf16x8*>(sC);
    int lsw = lane ^ 32;              // swapped-half lane for the [m'|h'] operand

    #pragma unroll 2
    for (int kt = 0; kt < KT_PER_CHUNK; ++kt) {
        bf16x8 c1 = sA8[kt * 64 + lane];
        bf16x8 c2 = sA8[kt * 64 + lsw];
        bf16x8 c3 = sC8[kt * 64 + lane];
        #pragma unroll
        for (int r = 0; r < 2; ++r) {
            f32x4 acc = {0.f, 0.f, 0.f, 0.f};
            acc = __builtin_amdgcn_mfma_f32_16x16x32_bf16(a_hm[r], c1, acc, 0, 0, 0); // hh+mm
            acc = __builtin_amdgcn_mfma_f32_16x16x32_bf16(a_hm[r], c2, acc, 0, 0, 0); // hm+mh
            acc = __builtin_amdgcn_mfma_f32_16x16x32_bf16(a_lh[r], c3, acc, 0, 0, 0); // lh+hl
            #pragma unroll
            for (int i = 0; i < 4; ++i) {
                bool gt = acc[i] > best[r][i];
                best[r][i] = gt ? acc[i] : best[r][i];
                bidx[r][i] = gt ? kt     : bidx[r][i];
            }
        }
    }

    // Pack (score, idx) into u64 key, 4-round 16-lane max reduce, 1 store/row.
    // Key = mono(score)<<32 | ~idx : max => higher score, then lower index on
    // ties (bitwise-identical semantics to the verified round-2 path).
    int colc = lane & 15;
    #pragma unroll
    for (int r = 0; r < 2; ++r) {
        #pragma unroll
        for (int i = 0; i < 4; ++i) {
            unsigned u    = __float_as_uint(best[r][i]);
            unsigned mono = (u & 0x80000000u) ? ~u : (u | 0x80000000u);
            unsigned kg   = (unsigned)(kc * 256 + bidx[r][i] * 16 + colc);
            unsigned long long key = ((unsigned long long)mono << 32) | (unsigned)(~kg);
            #pragma unroll
            for (int off = 1; off <= 8; off <<= 1) {
                unsigned long long ok =
                    (((unsigned long long)(unsigned)__shfl_xor((int)(key >> 32), off, 64)) << 32) |
                    (unsigned)__shfl_xor((int)(unsigned)key, off, 64);
                key = (ok > key) ? ok : key;
            }
            if (colc == 0) {
                int row = (rt0 + r) * 16 + (lane >> 4) * 4 + i;
                if (row < M_ROWS) part[(size_t)row * NCHUNK + kc] = key;
            }
        }
    }
}

// ---------- Decode: reduce 32 per-chunk keys per row -> int32 index ----------
__global__ __launch_bounds__(256) void decode_kernel(const unsigned long long* __restrict__ part,
                                                     int* __restrict__ out) {
    int t    = threadIdx.x;
    int lane = t & 63;
    int wv   = t >> 6;
    int row  = blockIdx.x * 32 + wv * 8 + (lane >> 3);
    int j    = lane & 7;
    const unsigned long long* p = part + (size_t)row * NCHUNK + j * 4;
    unsigned long long k0 = p[0], k1 = p[1], k2 = p[2], k3 = p[3];
    k0 = k0 > k1 ? k0 : k1;
    k2 = k2 > k3 ? k2 : k3;
    unsigned long long key = k0 > k2 ? k0 : k2;
    #pragma unroll
    for (int off = 1; off <= 4; off <<= 1) {
        unsigned long long ok =
            (((unsigned long long)(unsigned)__shfl_xor((int)(key >> 32), off, 64)) << 32) |
            (unsigned)__shfl_xor((int)(unsigned)key, off, 64);
        key = (ok > key) ? ok : key;
    }
    if (j == 0) out[row] = (int)(~(unsigned)(key & 0xFFFFFFFFull));
}

extern "C" void kernel_launch(void* const* d_in, const int* in_sizes, int n_in,
                              void* d_out, int out_size, void* d_ws, size_t ws_size,
                              hipStream_t stream) {
    const float* hs = (const float*)d_in[0];   // [8,2000,320]
    const float* P  = (const float*)d_in[1];   // [1,320,16]
    const float* CB = (const float*)d_in[2];   // [1,8192,16]
    int* out = (int*)d_out;                    // [8,1,2000] int32

    char* ws = (char*)d_ws;
    unsigned short* Xa  = (unsigned short*)(ws + XA_OFF);
    unsigned short* Xb  = (unsigned short*)(ws + XB_OFF);
    unsigned short* CBa = (unsigned short*)(ws + CBA_OFF);
    unsigned short* CBc = (unsigned short*)(ws + CBC_OFF);
    unsigned long long* part = (unsigned long long*)(ws + PART_OFF);

    prep_kernel<<<dim3(378), dim3(256), 0, stream>>>(hs, P, CB, Xa, Xb, CBa, CBc);
    score_kernel<<<dim3(NRB * NCHUNK), dim3(256), 0, stream>>>(Xa, Xb, CBa, CBc, part);
    decode_kernel<<<dim3(M_ROWS / 32), dim3(256), 0, stream>>>(part, out);
}

// Round 10
// 57.587 us; speedup vs baseline: 1.0390x; 1.0390x over previous
//
#include <hip/hip_runtime.h>
#include <stdint.h>

// Problem constants
#define M_ROWS   16000        // B*T
#define N_RT_PAD 1008         // 63 row-blocks x 16 tiles
#define D_IN     320
#define E_DIM    16
#define K_CB     8192
#define NCHUNK   32           // k-chunks (16 k-tiles each)
#define KT_PER_CHUNK 16
#define RPT      4            // row-tiles per wave
#define NRB      63           // row-blocks (16 rt each; 4 rt per wave)

typedef __attribute__((ext_vector_type(8))) short bf16x8;
typedef __attribute__((ext_vector_type(4))) float f32x4;

// Workspace layout (bytes)
#define XA_OFF   0u                       // [1008 tiles][64 lanes][8 bf16]  (h|m)
#define XB_OFF   1032192u                 // same shape                       (l|h)
#define CBA_OFF  2064384u                 // [512 ktiles][64 lanes][8 bf16]  (h'|m')
#define CBC_OFF  2588672u                 // same                             (h'|l')
#define PART_OFF 3112960u                 // [16000 rows][32 kc] u64 partials

#define AS1 __attribute__((address_space(1)))
#define AS3 __attribute__((address_space(3)))

__device__ __forceinline__ unsigned short f2bf(float x) {
    union { float f; unsigned u; } v; v.f = x;
    unsigned r = v.u + 0x7FFFu + ((v.u >> 16) & 1u);   // round-to-nearest-even
    return (unsigned short)(r >> 16);
}
__device__ __forceinline__ float bf2f(unsigned short b) {
    union { unsigned u; float f; } v; v.u = ((unsigned)b) << 16; return v.f;
}

// ---------- Fused prep: projection-split-pack (blocks 0..249) + codebook
// split-pack (blocks 250..377). Math identical to rounds 2-8. ----------
__global__ __launch_bounds__(256) void prep_kernel(const float* __restrict__ hs,
                                                   const float* __restrict__ P,
                                                   const float* __restrict__ CB,
                                                   unsigned short* __restrict__ Xa,
                                                   unsigned short* __restrict__ Xb,
                                                   unsigned short* __restrict__ CBa,
                                                   unsigned short* __restrict__ CBc) {
    int bid = blockIdx.x;
    int t   = threadIdx.x;
    if (bid < 250) {
        int row = bid * 64 + (t >> 2);
        int eq  = t & 3;
        if (row >= M_ROWS) return;
        const float* hrow = hs + (size_t)row * D_IN;
        float ax = 0.f, ay = 0.f, az = 0.f, aw = 0.f;
        #pragma unroll 4
        for (int d = 0; d < D_IN; d += 4) {
            float4 h4 = *reinterpret_cast<const float4*>(hrow + d);
            float4 p0 = *reinterpret_cast<const float4*>(P + (size_t)(d + 0) * E_DIM + eq * 4);
            float4 p1 = *reinterpret_cast<const float4*>(P + (size_t)(d + 1) * E_DIM + eq * 4);
            float4 p2 = *reinterpret_cast<const float4*>(P + (size_t)(d + 2) * E_DIM + eq * 4);
            float4 p3 = *reinterpret_cast<const float4*>(P + (size_t)(d + 3) * E_DIM + eq * 4);
            ax += h4.x * p0.x + h4.y * p1.x + h4.z * p2.x + h4.w * p3.x;
            ay += h4.x * p0.y + h4.y * p1.y + h4.z * p2.y + h4.w * p3.y;
            az += h4.x * p0.z + h4.y * p1.z + h4.z * p2.z + h4.w * p3.z;
            aw += h4.x * p0.w + h4.y * p1.w + h4.z * p2.w + h4.w * p3.w;
        }
        float v[4] = {ax, ay, az, aw};
        ushort4 h, m, l;
        unsigned short* hp = (unsigned short*)&h;
        unsigned short* mp = (unsigned short*)&m;
        unsigned short* lp = (unsigned short*)&l;
        #pragma unroll
        for (int i = 0; i < 4; ++i) {
            unsigned short hb = f2bf(v[i]);      float r1 = v[i] - bf2f(hb);
            unsigned short mb = f2bf(r1);        float r2 = r1 - bf2f(mb);
            unsigned short lb = f2bf(r2);        // exact: v = h + m + l
            hp[i] = hb; mp[i] = mb; lp[i] = lb;
        }
        int rt = row >> 4, rl = row & 15;
        int g  = eq >> 1;
        int j0 = (eq & 1) * 4;
        size_t base = (size_t)rt * 512;
        *reinterpret_cast<ushort4*>(Xa + base + ((g    ) * 16 + rl) * 8 + j0) = h;
        *reinterpret_cast<ushort4*>(Xa + base + ((2 + g) * 16 + rl) * 8 + j0) = m;
        *reinterpret_cast<ushort4*>(Xb + base + ((g    ) * 16 + rl) * 8 + j0) = l;
        *reinterpret_cast<ushort4*>(Xb + base + ((2 + g) * 16 + rl) * 8 + j0) = h;
    } else {
        int bid2 = bid - 250;                     // 0..127
        int c  = bid2 * 64 + (t >> 2);
        int eq = t & 3;
        float4 v4 = *reinterpret_cast<const float4*>(CB + (size_t)c * E_DIM + eq * 4);
        float v[4] = {v4.x, v4.y, v4.z, v4.w};
        ushort4 h, m, l;
        unsigned short* hp = (unsigned short*)&h;
        unsigned short* mp = (unsigned short*)&m;
        unsigned short* lp = (unsigned short*)&l;
        #pragma unroll
        for (int i = 0; i < 4; ++i) {
            unsigned short hb = f2bf(v[i]);      float r1 = v[i] - bf2f(hb);
            unsigned short mb = f2bf(r1);        float r2 = r1 - bf2f(mb);
            unsigned short lb = f2bf(r2);
            hp[i] = hb; mp[i] = mb; lp[i] = lb;
        }
        int kt = c >> 4, cl = c & 15;
        int g  = eq >> 1;
        int j0 = (eq & 1) * 4;
        size_t base = (size_t)kt * 512;
        *reinterpret_cast<ushort4*>(CBa + base + ((g    ) * 16 + cl) * 8 + j0) = h;
        *reinterpret_cast<ushort4*>(CBa + base + ((2 + g) * 16 + cl) * 8 + j0) = m;
        *reinterpret_cast<ushort4*>(CBc + base + ((g    ) * 16 + cl) * 8 + j0) = h;
        *reinterpret_cast<ushort4*>(CBc + base + ((2 + g) * 16 + cl) * 8 + j0) = l;
    }
}

// ---------- MFMA score + fused argmax; whole-chunk LDS B staging ----------
// 2016 blocks x 256 threads (4 waves). Block stages its k-chunk's B fragments
// (32 KB) via global_load_lds (0 VGPR cost); ONE __syncthreads; barrier-free
// inner loop of ds_read_b128 + 3 chained MFMAs (exact fp32-split scores) +
// strict-gt argmax. Wave owns 4 row-tiles => 4 independent MFMA chains per kt.
// c2 ([m'|h']) = c1 fragment read at lane^32 (verified round-2/-8 path).
__global__ __launch_bounds__(256, 4) void score_kernel(const unsigned short* __restrict__ Xa,
                                                       const unsigned short* __restrict__ Xb,
                                                       const unsigned short* __restrict__ CBa,
                                                       const unsigned short* __restrict__ CBc,
                                                       unsigned long long* __restrict__ part) {
    __shared__ unsigned short sA[KT_PER_CHUNK * 512];   // 16 KB  (h'|m')
    __shared__ unsigned short sC[KT_PER_CHUNK * 512];   // 16 KB  (h'|l')

    int t    = threadIdx.x;
    int lane = t & 63;
    int w    = t >> 6;                // 0..3
    int flat = blockIdx.x;            // 0..2015
    int xcd  = flat & 7;
    int idx  = flat >> 3;             // 0..251
    int kc   = xcd * 4 + idx / NRB;   // 0..31, clustered per XCD
    int rb   = idx % NRB;             // 0..62
    int rt0  = rb * 16 + w * RPT;

    // Issue A-fragment loads early (overlap with staging).
    bf16x8 a_hm[RPT], a_lh[RPT];
    #pragma unroll
    for (int r = 0; r < RPT; ++r) {
        a_hm[r] = *reinterpret_cast<const bf16x8*>(Xa + ((size_t)(rt0 + r) * 64 + lane) * 8);
        a_lh[r] = *reinterpret_cast<const bf16x8*>(Xb + ((size_t)(rt0 + r) * 64 + lane) * 8);
    }

    // Stage both B streams for the whole k-chunk (4 glds rounds each).
    {
        const unsigned char* ga = (const unsigned char*)(CBa + (size_t)kc * KT_PER_CHUNK * 512);
        const unsigned char* gc = (const unsigned char*)(CBc + (size_t)kc * KT_PER_CHUNK * 512);
        unsigned char* la = (unsigned char*)sA;
        unsigned char* lc = (unsigned char*)sC;
        int wo = w * 1024 + lane * 16;
        #pragma unroll
        for (int q = 0; q < 4; ++q)
            __builtin_amdgcn_global_load_lds((const AS1 void*)(ga + q * 4096 + wo),
                                             (AS3 void*)(la + q * 4096 + w * 1024), 16, 0, 0);
        #pragma unroll
        for (int q = 0; q < 4; ++q)
            __builtin_amdgcn_global_load_lds((const AS1 void*)(gc + q * 4096 + wo),
                                             (AS3 void*)(lc + q * 4096 + w * 1024), 16, 0, 0);
    }

    float best[RPT][4];
    int   bidx[RPT][4];
    #pragma unroll
    for (int r = 0; r < RPT; ++r)
        #pragma unroll
        for (int i = 0; i < 4; ++i) { best[r][i] = -3.0e38f; bidx[r][i] = 0; }

    __syncthreads();   // compiler emits vmcnt(0) drain: staging + A-loads done

    const bf16x8* sA8 = reinterpret_cast<const bf16x8*>(sA);
    const bf16x8* sC8 = reinterpret_cast<const bf16x8*>(sC);
    int lsw = lane ^ 32;              // swapped-half lane for the [m'|h'] operand

    #pragma unroll 2
    for (int kt = 0; kt < KT_PER_CHUNK; ++kt) {
        bf16x8 c1 = sA8[kt * 64 + lane];
        bf16x8 c2 = sA8[kt * 64 + lsw];
        bf16x8 c3 = sC8[kt * 64 + lane];
        #pragma unroll
        for (int r = 0; r < RPT; ++r) {
            f32x4 acc = {0.f, 0.f, 0.f, 0.f};
            acc = __builtin_amdgcn_mfma_f32_16x16x32_bf16(a_hm[r], c1, acc, 0, 0, 0); // hh+mm
            acc = __builtin_amdgcn_mfma_f32_16x16x32_bf16(a_hm[r], c2, acc, 0, 0, 0); // hm+mh
            acc = __builtin_amdgcn_mfma_f32_16x16x32_bf16(a_lh[r], c3, acc, 0, 0, 0); // lh+hl
            #pragma unroll
            for (int i = 0; i < 4; ++i) {
                bool gt = acc[i] > best[r][i];
                best[r][i] = gt ? acc[i] : best[r][i];
                bidx[r][i] = gt ? kt     : bidx[r][i];
            }
        }
    }

    // Pack (score, idx) into u64 key, 4-round 16-lane max reduce, 1 store/row.
    // Key = mono(score)<<32 | ~idx : max => higher score, then lower index on
    // ties (bitwise-identical semantics to the verified round-2 path).
    int colc = lane & 15;
    #pragma unroll
    for (int r = 0; r < RPT; ++r) {
        #pragma unroll
        for (int i = 0; i < 4; ++i) {
            unsigned u    = __float_as_uint(best[r][i]);
            unsigned mono = (u & 0x80000000u) ? ~u : (u | 0x80000000u);
            unsigned kg   = (unsigned)(kc * 256 + bidx[r][i] * 16 + colc);
            unsigned long long key = ((unsigned long long)mono << 32) | (unsigned)(~kg);
            #pragma unroll
            for (int off = 1; off <= 8; off <<= 1) {
                unsigned long long ok =
                    (((unsigned long long)(unsigned)__shfl_xor((int)(key >> 32), off, 64)) << 32) |
                    (unsigned)__shfl_xor((int)(unsigned)key, off, 64);
                key = (ok > key) ? ok : key;
            }
            if (colc == 0) {
                int row = (rt0 + r) * 16 + (lane >> 4) * 4 + i;
                if (row < M_ROWS) part[(size_t)row * NCHUNK + kc] = key;
            }
        }
    }
}

// ---------- Decode: reduce 32 per-chunk keys per row -> int32 index ----------
__global__ __launch_bounds__(256) void decode_kernel(const unsigned long long* __restrict__ part,
                                                     int* __restrict__ out) {
    int t    = threadIdx.x;
    int lane = t & 63;
    int wv   = t >> 6;
    int row  = blockIdx.x * 32 + wv * 8 + (lane >> 3);
    int j    = lane & 7;
    const unsigned long long* p = part + (size_t)row * NCHUNK + j * 4;
    unsigned long long k0 = p[0], k1 = p[1], k2 = p[2], k3 = p[3];
    k0 = k0 > k1 ? k0 : k1;
    k2 = k2 > k3 ? k2 : k3;
    unsigned long long key = k0 > k2 ? k0 : k2;
    #pragma unroll
    for (int off = 1; off <= 4; off <<= 1) {
        unsigned long long ok =
            (((unsigned long long)(unsigned)__shfl_xor((int)(key >> 32), off, 64)) << 32) |
            (unsigned)__shfl_xor((int)(unsigned)key, off, 64);
        key = (ok > key) ? ok : key;
    }
    if (j == 0) out[row] = (int)(~(unsigned)(key & 0xFFFFFFFFull));
}

extern "C" void kernel_launch(void* const* d_in, const int* in_sizes, int n_in,
                              void* d_out, int out_size, void* d_ws, size_t ws_size,
                              hipStream_t stream) {
    const float* hs = (const float*)d_in[0];   // [8,2000,320]
    const float* P  = (const float*)d_in[1];   // [1,320,16]
    const float* CB = (const float*)d_in[2];   // [1,8192,16]
    int* out = (int*)d_out;                    // [8,1,2000] int32

    char* ws = (char*)d_ws;
    unsigned short* Xa  = (unsigned short*)(ws + XA_OFF);
    unsigned short* Xb  = (unsigned short*)(ws + XB_OFF);
    unsigned short* CBa = (unsigned short*)(ws + CBA_OFF);
    unsigned short* CBc = (unsigned short*)(ws + CBC_OFF);
    unsigned long long* part = (unsigned long long*)(ws + PART_OFF);

    prep_kernel<<<dim3(378), dim3(256), 0, stream>>>(hs, P, CB, Xa, Xb, CBa, CBc);
    score_kernel<<<dim3(NRB * NCHUNK), dim3(256), 0, stream>>>(Xa, Xb, CBa, CBc, part);
    decode_kernel<<<dim3(M_ROWS / 32), dim3(256), 0, stream>>>(part, out);
}